// Round 3
// baseline (447.348 us; speedup 1.0000x reference)
//
#include <hip/hip_runtime.h>
#include <hip/hip_bf16.h>
#include <stdint.h>
#include <stddef.h>

typedef __bf16 bf16_t;
typedef __bf16 bf16x4_t __attribute__((ext_vector_type(4)));
typedef __bf16 bf16x8_t __attribute__((ext_vector_type(8)));
typedef float f32x4 __attribute__((ext_vector_type(4)));

#define D_MODEL 2048
#define NHEADS 16
#define HDIM 128
#define SEQ 2048
#define BATCH 2
#define MTOT (BATCH * SEQ) /* 4096 */
#define SCALE_F 0.08838834764831845f /* 1/sqrt(128) */
#define LOG2E 1.4426950408889634f
#define QSCALE (SCALE_F * LOG2E)

#define AS1 __attribute__((address_space(1)))
#define AS3 __attribute__((address_space(3)))

__device__ __forceinline__ void load_lds16(const bf16_t* g, bf16_t* l) {
  __builtin_amdgcn_global_load_lds((AS1 void*)(g), (AS3 void*)(l), 16, 0, 0);
}

// ---------------------------------------------------------------- casts fp32->bf16
__global__ void cast_kernel(const float* __restrict__ src, bf16_t* __restrict__ dst, int n4) {
  int i = blockIdx.x * blockDim.x + threadIdx.x;
  if (i < n4) {
    float4 v = ((const float4*)src)[i];
    bf16x4_t o;
    o.x = (bf16_t)v.x; o.y = (bf16_t)v.y; o.z = (bf16_t)v.z; o.w = (bf16_t)v.w;
    ((bf16x4_t*)dst)[i] = o;
  }
}

__global__ void cast4_kernel(const float* __restrict__ s0, const float* __restrict__ s1,
                             const float* __restrict__ s2, const float* __restrict__ s3,
                             bf16_t* __restrict__ dst, int n4) {
  int i = blockIdx.x * blockDim.x + threadIdx.x;
  int y = blockIdx.y;
  if (i < n4) {
    const float* src = (y == 0) ? s0 : (y == 1) ? s1 : (y == 2) ? s2 : s3;
    float4 v = ((const float4*)src)[i];
    bf16x4_t o;
    o.x = (bf16_t)v.x; o.y = (bf16_t)v.y; o.z = (bf16_t)v.z; o.w = (bf16_t)v.w;
    ((bf16x4_t*)(dst + (size_t)y * D_MODEL * D_MODEL / 4 * 4))[i] = o;
  }
}

// ---------------------------------------------------------------- GEMM  C = A @ B^T (+bias)
// BK=64, XOR chunk-swizzled LDS. mode 0: N=6144 (q|k|v) -> Q (prescaled by QSCALE), K,
// V transposed. mode 1: N=2048 -> fp32 out + bias.
__global__ __launch_bounds__(256) void gemm_fused(
    const bf16_t* __restrict__ A, const bf16_t* __restrict__ Bm, int mode,
    const float* __restrict__ bias0, const float* __restrict__ bias1,
    const float* __restrict__ bias2,
    bf16_t* __restrict__ Qo, bf16_t* __restrict__ Ko, bf16_t* __restrict__ Vto,
    float* __restrict__ Out) {
  const int K = 2048;
  __shared__ __align__(16) bf16_t lA[128 * 64];
  __shared__ __align__(16) bf16_t lB[128 * 64];
  const int m0 = blockIdx.x * 128;
  const int n0 = blockIdx.y * 128;
  const int t = threadIdx.x;
  const int w = t >> 6, lane = t & 63;
  const int wm = w & 1, wn = w >> 1;
  const int la = lane & 15, lb = lane >> 4;

  f32x4 acc[4][4];
  f32x4 zero = {0.f, 0.f, 0.f, 0.f};
#pragma unroll
  for (int i = 0; i < 4; i++)
#pragma unroll
    for (int j = 0; j < 4; j++) acc[i][j] = zero;

  const int row0 = t >> 3, cc = t & 7;
  const int ccs = cc ^ (row0 & 7);
  const bf16_t* gA = A + (size_t)(m0 + row0) * K + ccs * 8;
  const bf16_t* gB = Bm + (size_t)(n0 + row0) * K + ccs * 8;
  bf16_t* sA = lA + t * 8;
  bf16_t* sB = lB + t * 8;

  for (int k0 = 0; k0 < K; k0 += 64) {
    __syncthreads();
#pragma unroll
    for (int i = 0; i < 4; i++)
      load_lds16(gA + k0 + (size_t)(32 * i) * K, sA + 2048 * i);
#pragma unroll
    for (int i = 0; i < 4; i++)
      load_lds16(gB + k0 + (size_t)(32 * i) * K, sB + 2048 * i);
    __syncthreads();
#pragma unroll
    for (int ks = 0; ks < 2; ks++) {
      bf16x8_t af[4], bfr[4];
#pragma unroll
      for (int mt = 0; mt < 4; mt++) {
        int row = wm * 64 + mt * 16 + la;
        af[mt] = *(const bf16x8_t*)(lA + row * 64 + (((ks * 4 + lb) ^ (la & 7)) * 8));
      }
#pragma unroll
      for (int nt = 0; nt < 4; nt++) {
        int row = wn * 64 + nt * 16 + la;
        bfr[nt] = *(const bf16x8_t*)(lB + row * 64 + (((ks * 4 + lb) ^ (la & 7)) * 8));
      }
#pragma unroll
      for (int mt = 0; mt < 4; mt++)
#pragma unroll
        for (int nt = 0; nt < 4; nt++)
          acc[mt][nt] = __builtin_amdgcn_mfma_f32_16x16x32_bf16(af[mt], bfr[nt], acc[mt][nt], 0, 0, 0);
    }
  }

  if (mode == 0) {
#pragma unroll
    for (int mt = 0; mt < 4; mt++) {
#pragma unroll
      for (int nt = 0; nt < 4; nt++) {
        int m = m0 + wm * 64 + mt * 16 + lb * 4;
        int n = n0 + wn * 64 + nt * 16 + la;
        int b = m >> 11, s = m & 2047;
        int which = n >> 11, hd = n & 2047;
        int h = hd >> 7, d = hd & 127;
        float bv = (which == 0 ? bias0 : which == 1 ? bias1 : bias2)[hd];
        f32x4 v = acc[mt][nt];
        if (which == 2) {
          bf16_t* dst = Vto + ((size_t)(b * NHEADS + h) * HDIM + d) * SEQ + s;
          bf16x4_t pk;
          pk.x = (bf16_t)(v.x + bv); pk.y = (bf16_t)(v.y + bv);
          pk.z = (bf16_t)(v.z + bv); pk.w = (bf16_t)(v.w + bv);
          *(bf16x4_t*)dst = pk;
        } else {
          float sc = (which == 0) ? QSCALE : 1.0f;  // pre-scale Q by 1/sqrt(d)*log2e
          bf16_t* dst = (which == 0 ? Qo : Ko) + ((size_t)(b * NHEADS + h) * SEQ + s) * HDIM + d;
          dst[0]        = (bf16_t)((v.x + bv) * sc);
          dst[HDIM]     = (bf16_t)((v.y + bv) * sc);
          dst[2 * HDIM] = (bf16_t)((v.z + bv) * sc);
          dst[3 * HDIM] = (bf16_t)((v.w + bv) * sc);
        }
      }
    }
  } else {
#pragma unroll
    for (int mt = 0; mt < 4; mt++) {
#pragma unroll
      for (int nt = 0; nt < 4; nt++) {
        int m = m0 + wm * 64 + mt * 16 + lb * 4;
        int n = n0 + wn * 64 + nt * 16 + la;
        float bv = bias0[n];
        f32x4 v = acc[mt][nt];
        float* dst = Out + (size_t)m * D_MODEL + n;
        dst[0]           = v.x + bv;
        dst[D_MODEL]     = v.y + bv;
        dst[2 * D_MODEL] = v.z + bv;
        dst[3 * D_MODEL] = v.w + bv;
      }
    }
  }
}

// ---------------------------------------------------------------- causal flash attention
// S^T = K Q^T formulation: per-lane q-column softmax (2 shuffles/reduce), O^T accumulation.
// Grid: 24 pieces x 32 bh. Pieces 0..15: qt=8+(p>>1), half=p&1 (split-j, partial out).
// Pieces 16..23: qt=p-16 (full, direct out). Q is pre-scaled by QSCALE.
__global__ __launch_bounds__(256, 3) void flash_attn(
    const bf16_t* __restrict__ Q, const bf16_t* __restrict__ Kg,
    const bf16_t* __restrict__ Vt, bf16_t* __restrict__ O,
    bf16_t* __restrict__ PO, float* __restrict__ ML) {
  __shared__ __align__(16) bf16_t lK[64 * 128];  // [j][d], chunk-swizzled
  __shared__ __align__(16) bf16_t lV[128 * 64];  // [d][j], chunk-swizzled
  __shared__ __align__(16) bf16_t lP[128 * 72];  // P^T stored as [q][j], stride 72
  const int g = blockIdx.x;
  const int piece = g >> 5, bh = g & 31;
  int qt, kt0, kt1, half;
  bool partial;
  if (piece < 16) {
    qt = 8 + (piece >> 1); half = piece & 1; partial = true;
    kt0 = half ? (qt + 1) : 0;
    kt1 = half ? (2 * qt + 2) : (qt + 1);
  } else {
    qt = piece - 16; half = 0; partial = false;
    kt0 = 0; kt1 = 2 * qt + 2;
  }
  const int q0 = qt * 128;
  const int t = threadIdx.x;
  const int w = t >> 6, lane = t & 63;
  const int la = lane & 15, lb = lane >> 4;
  const int qloc = w * 32 + la;  // + mt*16

  const bf16_t* Qb = Q + (size_t)bh * SEQ * HDIM;
  const bf16_t* Kb = Kg + (size_t)bh * SEQ * HDIM;
  const bf16_t* Vb = Vt + (size_t)bh * HDIM * SEQ;

  // Q fragments (B-operand): lane needs Q[q0+qloc+16mt][32ks+8lb+i]
  bf16x8_t qf[2][4];
#pragma unroll
  for (int mt = 0; mt < 2; mt++)
#pragma unroll
    for (int ks = 0; ks < 4; ks++)
      qf[mt][ks] = *(const bf16x8_t*)(Qb + (size_t)(q0 + qloc + mt * 16) * HDIM + ks * 32 + lb * 8);

  f32x4 oacc[2][8];  // O^T: rows d = dt*16+lb*4+r, col q = qloc+16mt
  float mr[2] = {-3.0e38f, -3.0e38f}, lr[2] = {0.f, 0.f};
  f32x4 zero = {0.f, 0.f, 0.f, 0.f};
#pragma unroll
  for (int mt = 0; mt < 2; mt++)
#pragma unroll
    for (int dt = 0; dt < 8; dt++) oacc[mt][dt] = zero;

  for (int kt = kt0; kt < kt1; kt++) {
    const int j0 = kt * 64;
    __syncthreads();
#pragma unroll
    for (int i = 0; i < 4; i++) {
      int slot = t + 256 * i;
      int j = slot >> 4, cc = slot & 15;
      load_lds16(Kb + (size_t)(j0 + j) * HDIM + ((cc ^ (j & 15)) * 8), lK + slot * 8);
    }
#pragma unroll
    for (int i = 0; i < 4; i++) {
      int slot = t + 256 * i;
      int d = slot >> 3, jc = slot & 7;
      load_lds16(Vb + (size_t)d * SEQ + j0 + ((jc ^ (d & 7)) * 8), lV + slot * 8);
    }
    __syncthreads();

    // S^T = K @ Q^T : rows j (4 nt tiles), cols q (2 mt tiles)
    f32x4 st[4][2];
#pragma unroll
    for (int nt = 0; nt < 4; nt++)
#pragma unroll
      for (int mt = 0; mt < 2; mt++) st[nt][mt] = zero;
#pragma unroll
    for (int ks = 0; ks < 4; ks++) {
#pragma unroll
      for (int nt = 0; nt < 4; nt++) {
        int j = nt * 16 + la;
        int cc = (lb + 4 * ks) ^ (j & 15);
        bf16x8_t kf = *(const bf16x8_t*)(lK + j * 128 + cc * 8);
#pragma unroll
        for (int mt = 0; mt < 2; mt++)
          st[nt][mt] = __builtin_amdgcn_mfma_f32_16x16x32_bf16(kf, qf[mt][ks], st[nt][mt], 0, 0, 0);
      }
    }

    const bool dm = (j0 + 64 > q0);  // diagonal-straddling tile (wave-uniform)
#pragma unroll
    for (int mt = 0; mt < 2; mt++) {
      int qg = q0 + qloc + mt * 16;
      if (dm) {
#pragma unroll
        for (int nt = 0; nt < 4; nt++)
#pragma unroll
          for (int r = 0; r < 4; r++)
            if (j0 + nt * 16 + lb * 4 + r > qg) st[nt][mt][r] = -3.0e38f;
      }
      float tm = -3.0e38f;
#pragma unroll
      for (int nt = 0; nt < 4; nt++)
#pragma unroll
        for (int r = 0; r < 4; r++) tm = fmaxf(tm, st[nt][mt][r]);
      tm = fmaxf(tm, __shfl_xor(tm, 16));
      tm = fmaxf(tm, __shfl_xor(tm, 32));
      float mnew = fmaxf(mr[mt], tm);
      float alpha = exp2f(mr[mt] - mnew);
      mr[mt] = mnew;
      lr[mt] *= alpha;
#pragma unroll
      for (int dt = 0; dt < 8; dt++) oacc[mt][dt] *= alpha;
      float s = 0.f;
#pragma unroll
      for (int nt = 0; nt < 4; nt++) {
        f32x4 p;
#pragma unroll
        for (int r = 0; r < 4; r++) {
          p[r] = exp2f(st[nt][mt][r] - mnew);
          s += p[r];
        }
        bf16x4_t pk;
        pk.x = (bf16_t)p[0]; pk.y = (bf16_t)p[1]; pk.z = (bf16_t)p[2]; pk.w = (bf16_t)p[3];
        *(bf16x4_t*)(lP + (qloc + mt * 16) * 72 + nt * 16 + lb * 4) = pk;  // packed b64
      }
      s += __shfl_xor(s, 16);
      s += __shfl_xor(s, 32);
      lr[mt] += s;
    }

    // O^T += V^T P^T : A = Vt rows d, B = P^T (lane reads its own wave's q rows)
    bf16x8_t pf[2][2];
#pragma unroll
    for (int mt = 0; mt < 2; mt++)
#pragma unroll
      for (int ks = 0; ks < 2; ks++)
        pf[mt][ks] = *(const bf16x8_t*)(lP + (qloc + mt * 16) * 72 + ks * 32 + lb * 8);
#pragma unroll
    for (int ks = 0; ks < 2; ks++) {
#pragma unroll
      for (int dt = 0; dt < 8; dt++) {
        int d = dt * 16 + la;
        int jc = (lb + 4 * ks) ^ (d & 7);
        bf16x8_t vf = *(const bf16x8_t*)(lV + d * 64 + jc * 8);
#pragma unroll
        for (int mt = 0; mt < 2; mt++)
          oacc[mt][dt] = __builtin_amdgcn_mfma_f32_16x16x32_bf16(vf, pf[mt][ks], oacc[mt][dt], 0, 0, 0);
      }
    }
  }

  if (!partial) {
    // O[b][s=q][h*128+d], 4 consecutive d per store
    const int b = bh >> 4, h = bh & 15;
#pragma unroll
    for (int mt = 0; mt < 2; mt++) {
      float inv = 1.0f / lr[mt];
      int q = q0 + qloc + mt * 16;
      bf16_t* dst = O + ((size_t)b * SEQ + q) * D_MODEL + h * HDIM + lb * 4;
#pragma unroll
      for (int dt = 0; dt < 8; dt++) {
        f32x4 v = oacc[mt][dt];
        bf16x4_t pk;
        pk.x = (bf16_t)(v[0] * inv); pk.y = (bf16_t)(v[1] * inv);
        pk.z = (bf16_t)(v[2] * inv); pk.w = (bf16_t)(v[3] * inv);
        *(bf16x4_t*)(dst + dt * 16) = pk;
      }
    }
  } else {
    const int slot = ((qt - 8) * 32 + bh) * 2 + half;
    bf16_t* pob = PO + (size_t)slot * 128 * 128;
#pragma unroll
    for (int mt = 0; mt < 2; mt++) {
      int q = qloc + mt * 16;
      bf16_t* dst = pob + (size_t)q * 128 + lb * 4;
#pragma unroll
      for (int dt = 0; dt < 8; dt++) {
        f32x4 v = oacc[mt][dt];
        bf16x4_t pk;
        pk.x = (bf16_t)v[0]; pk.y = (bf16_t)v[1];
        pk.z = (bf16_t)v[2]; pk.w = (bf16_t)v[3];
        *(bf16x4_t*)(dst + dt * 16) = pk;
      }
      if (lb == 0) {
        float2 ml = make_float2(mr[mt], lr[mt]);
        *(float2*)(ML + ((size_t)slot * 128 + q) * 2) = ml;
      }
    }
  }
}

// ---------------------------------------------------------------- merge split-j partials
__global__ void merge_kernel(const bf16_t* __restrict__ PO, const float* __restrict__ ML,
                             bf16_t* __restrict__ O) {
  const int qti = blockIdx.x >> 5, bh = blockIdx.x & 31;
  const int qt = 8 + qti;
  const int t = threadIdx.x;
  const int q = t >> 1, dh = (t & 1) * 64;
  const size_t s1 = ((size_t)(qti * 32 + bh)) * 2;
  const float* ml1 = ML + (s1 * 128 + q) * 2;
  const float* ml2 = ML + ((s1 + 1) * 128 + q) * 2;
  float m1 = ml1[0], l1 = ml1[1], m2 = ml2[0], l2 = ml2[1];
  float m = fmaxf(m1, m2);
  float w1 = exp2f(m1 - m), w2 = exp2f(m2 - m);
  float inv = 1.0f / (w1 * l1 + w2 * l2);
  w1 *= inv; w2 *= inv;
  const bf16_t* p1 = PO + (s1 * 128 + q) * 128 + dh;
  const bf16_t* p2 = PO + ((s1 + 1) * 128 + q) * 128 + dh;
  const int b = bh >> 4, h = bh & 15;
  bf16_t* dst = O + ((size_t)b * SEQ + qt * 128 + q) * D_MODEL + h * HDIM + dh;
#pragma unroll
  for (int i = 0; i < 8; i++) {
    bf16x8_t a = ((const bf16x8_t*)p1)[i];
    bf16x8_t c = ((const bf16x8_t*)p2)[i];
    bf16x8_t o;
#pragma unroll
    for (int e = 0; e < 8; e++)
      o[e] = (bf16_t)(w1 * (float)a[e] + w2 * (float)c[e]);
    ((bf16x8_t*)dst)[i] = o;
  }
}

// ---------------------------------------------------------------- launch
extern "C" void kernel_launch(void* const* d_in, const int* in_sizes, int n_in,
                              void* d_out, int out_size, void* d_ws, size_t ws_size,
                              hipStream_t stream) {
  (void)in_sizes; (void)n_in; (void)out_size; (void)ws_size;
  const float* x  = (const float*)d_in[0];
  const float* Wq = (const float*)d_in[2];
  const float* bq = (const float*)d_in[3];
  const float* Wk = (const float*)d_in[4];
  const float* bk = (const float*)d_in[5];
  const float* Wv = (const float*)d_in[6];
  const float* bv = (const float*)d_in[7];
  const float* Wo = (const float*)d_in[8];
  const float* bo = (const float*)d_in[9];
  float* out = (float*)d_out;

  const size_t NBF = (size_t)MTOT * D_MODEL * sizeof(bf16_t);    // 16.8 MB
  const size_t WBF = (size_t)D_MODEL * D_MODEL * sizeof(bf16_t); // 8.4 MB
  char* p = (char*)d_ws;
  bf16_t* xb   = (bf16_t*)p; p += NBF;       // reused as attention output O
  bf16_t* Wcat = (bf16_t*)p; p += 4 * WBF;   // [Wq|Wk|Wv|Wo] bf16
  bf16_t* Qb   = (bf16_t*)p; p += NBF;
  bf16_t* Kb   = (bf16_t*)p; p += NBF;
  bf16_t* Vtb  = (bf16_t*)p; p += NBF;
  bf16_t* Wob  = Wcat + (size_t)3 * D_MODEL * D_MODEL;
  bf16_t* Ob   = xb;
  // Partial buffers overlay the dead Wq|Wk|Wv bf16 slots (dead after QKV GEMM):
  bf16_t* PO = Wcat;                                    // 512 slots * 16384 bf16 = 16.8 MB
  float*  ML = (float*)(Wcat + (size_t)512 * 128 * 128); // 512 * 128 * 2 f32 = 0.5 MB

  const int WN4 = D_MODEL * D_MODEL / 4;
  const int XN4 = MTOT * D_MODEL / 4;
  cast_kernel<<<XN4 / 256, 256, 0, stream>>>(x, xb, XN4);
  cast4_kernel<<<dim3(WN4 / 256, 4), 256, 0, stream>>>(Wq, Wk, Wv, Wo, Wcat, WN4);

  gemm_fused<<<dim3(MTOT / 128, 6144 / 128), 256, 0, stream>>>(
      xb, Wcat, 0, bq, bk, bv, Qb, Kb, Vtb, nullptr);

  flash_attn<<<dim3(768), 256, 0, stream>>>(Qb, Kb, Vtb, Ob, PO, ML);
  merge_kernel<<<dim3(256), 256, 0, stream>>>(PO, ML, Ob);

  gemm_fused<<<dim3(MTOT / 128, D_MODEL / 128), 256, 0, stream>>>(
      Ob, Wob, 1, bo, nullptr, nullptr, nullptr, nullptr, nullptr, out);
}

// Round 4
// 405.909 us; speedup vs baseline: 1.1021x; 1.1021x over previous
//
#include <hip/hip_runtime.h>
#include <hip/hip_bf16.h>
#include <stdint.h>
#include <stddef.h>

typedef __bf16 bf16_t;
typedef __bf16 bf16x4_t __attribute__((ext_vector_type(4)));
typedef __bf16 bf16x8_t __attribute__((ext_vector_type(8)));
typedef float f32x4 __attribute__((ext_vector_type(4)));

#define D_MODEL 2048
#define NHEADS 16
#define HDIM 128
#define SEQ 2048
#define BATCH 2
#define MTOT (BATCH * SEQ) /* 4096 */
#define SCALE_F 0.08838834764831845f /* 1/sqrt(128) */
#define LOG2E 1.4426950408889634f
#define QSCALE (SCALE_F * LOG2E)
#define KT 32            /* flash K-tile */
#define NEGI -3.0e38f    /* mask value */
#define MINIT -1.0e30f   /* finite m sentinel: keeps exp2(masked - m) == 0 */

#define AS1 __attribute__((address_space(1)))
#define AS3 __attribute__((address_space(3)))

__device__ __forceinline__ void load_lds16(const bf16_t* g, bf16_t* l) {
  __builtin_amdgcn_global_load_lds((AS1 void*)(g), (AS3 void*)(l), 16, 0, 0);
}

// ---------------------------------------------------------------- casts fp32->bf16
__global__ void cast_kernel(const float* __restrict__ src, bf16_t* __restrict__ dst, int n4) {
  int i = blockIdx.x * blockDim.x + threadIdx.x;
  if (i < n4) {
    float4 v = ((const float4*)src)[i];
    bf16x4_t o;
    o.x = (bf16_t)v.x; o.y = (bf16_t)v.y; o.z = (bf16_t)v.z; o.w = (bf16_t)v.w;
    ((bf16x4_t*)dst)[i] = o;
  }
}

__global__ void cast4_kernel(const float* __restrict__ s0, const float* __restrict__ s1,
                             const float* __restrict__ s2, const float* __restrict__ s3,
                             bf16_t* __restrict__ dst, int n4) {
  int i = blockIdx.x * blockDim.x + threadIdx.x;
  int y = blockIdx.y;
  if (i < n4) {
    const float* src = (y == 0) ? s0 : (y == 1) ? s1 : (y == 2) ? s2 : s3;
    float4 v = ((const float4*)src)[i];
    bf16x4_t o;
    o.x = (bf16_t)v.x; o.y = (bf16_t)v.y; o.z = (bf16_t)v.z; o.w = (bf16_t)v.w;
    ((bf16x4_t*)(dst + (size_t)y * D_MODEL * D_MODEL / 4 * 4))[i] = o;
  }
}

// ---------------------------------------------------------------- GEMM  C = A @ B^T (+bias)
// BK=64, XOR chunk-swizzled LDS. mode 0: N=6144 (q|k|v) -> Q (prescaled by QSCALE), K,
// V transposed. mode 1: N=2048 -> fp32 out + bias.
__global__ __launch_bounds__(256) void gemm_fused(
    const bf16_t* __restrict__ A, const bf16_t* __restrict__ Bm, int mode,
    const float* __restrict__ bias0, const float* __restrict__ bias1,
    const float* __restrict__ bias2,
    bf16_t* __restrict__ Qo, bf16_t* __restrict__ Ko, bf16_t* __restrict__ Vto,
    float* __restrict__ Out) {
  const int K = 2048;
  __shared__ __align__(16) bf16_t lA[128 * 64];
  __shared__ __align__(16) bf16_t lB[128 * 64];
  const int m0 = blockIdx.x * 128;
  const int n0 = blockIdx.y * 128;
  const int t = threadIdx.x;
  const int w = t >> 6, lane = t & 63;
  const int wm = w & 1, wn = w >> 1;
  const int la = lane & 15, lb = lane >> 4;

  f32x4 acc[4][4];
  f32x4 zero = {0.f, 0.f, 0.f, 0.f};
#pragma unroll
  for (int i = 0; i < 4; i++)
#pragma unroll
    for (int j = 0; j < 4; j++) acc[i][j] = zero;

  const int row0 = t >> 3, cc = t & 7;
  const int ccs = cc ^ (row0 & 7);
  const bf16_t* gA = A + (size_t)(m0 + row0) * K + ccs * 8;
  const bf16_t* gB = Bm + (size_t)(n0 + row0) * K + ccs * 8;
  bf16_t* sA = lA + t * 8;
  bf16_t* sB = lB + t * 8;

  for (int k0 = 0; k0 < K; k0 += 64) {
    __syncthreads();
#pragma unroll
    for (int i = 0; i < 4; i++)
      load_lds16(gA + k0 + (size_t)(32 * i) * K, sA + 2048 * i);
#pragma unroll
    for (int i = 0; i < 4; i++)
      load_lds16(gB + k0 + (size_t)(32 * i) * K, sB + 2048 * i);
    __syncthreads();
#pragma unroll
    for (int ks = 0; ks < 2; ks++) {
      bf16x8_t af[4], bfr[4];
#pragma unroll
      for (int mt = 0; mt < 4; mt++) {
        int row = wm * 64 + mt * 16 + la;
        af[mt] = *(const bf16x8_t*)(lA + row * 64 + (((ks * 4 + lb) ^ (la & 7)) * 8));
      }
#pragma unroll
      for (int nt = 0; nt < 4; nt++) {
        int row = wn * 64 + nt * 16 + la;
        bfr[nt] = *(const bf16x8_t*)(lB + row * 64 + (((ks * 4 + lb) ^ (la & 7)) * 8));
      }
#pragma unroll
      for (int mt = 0; mt < 4; mt++)
#pragma unroll
        for (int nt = 0; nt < 4; nt++)
          acc[mt][nt] = __builtin_amdgcn_mfma_f32_16x16x32_bf16(af[mt], bfr[nt], acc[mt][nt], 0, 0, 0);
    }
  }

  if (mode == 0) {
#pragma unroll
    for (int mt = 0; mt < 4; mt++) {
#pragma unroll
      for (int nt = 0; nt < 4; nt++) {
        int m = m0 + wm * 64 + mt * 16 + lb * 4;
        int n = n0 + wn * 64 + nt * 16 + la;
        int b = m >> 11, s = m & 2047;
        int which = n >> 11, hd = n & 2047;
        int h = hd >> 7, d = hd & 127;
        float bv = (which == 0 ? bias0 : which == 1 ? bias1 : bias2)[hd];
        f32x4 v = acc[mt][nt];
        if (which == 2) {
          bf16_t* dst = Vto + ((size_t)(b * NHEADS + h) * HDIM + d) * SEQ + s;
          bf16x4_t pk;
          pk.x = (bf16_t)(v.x + bv); pk.y = (bf16_t)(v.y + bv);
          pk.z = (bf16_t)(v.z + bv); pk.w = (bf16_t)(v.w + bv);
          *(bf16x4_t*)dst = pk;
        } else {
          float sc = (which == 0) ? QSCALE : 1.0f;
          bf16_t* dst = (which == 0 ? Qo : Ko) + ((size_t)(b * NHEADS + h) * SEQ + s) * HDIM + d;
          dst[0]        = (bf16_t)((v.x + bv) * sc);
          dst[HDIM]     = (bf16_t)((v.y + bv) * sc);
          dst[2 * HDIM] = (bf16_t)((v.z + bv) * sc);
          dst[3 * HDIM] = (bf16_t)((v.w + bv) * sc);
        }
      }
    }
  } else {
#pragma unroll
    for (int mt = 0; mt < 4; mt++) {
#pragma unroll
      for (int nt = 0; nt < 4; nt++) {
        int m = m0 + wm * 64 + mt * 16 + lb * 4;
        int n = n0 + wn * 64 + nt * 16 + la;
        float bv = bias0[n];
        f32x4 v = acc[mt][nt];
        float* dst = Out + (size_t)m * D_MODEL + n;
        dst[0]           = v.x + bv;
        dst[D_MODEL]     = v.y + bv;
        dst[2 * D_MODEL] = v.z + bv;
        dst[3 * D_MODEL] = v.w + bv;
      }
    }
  }
}

// ---------------------------------------------------------------- causal flash attention
// K-tile 32, DOUBLE-BUFFERED staging: prefetch tile t+1 right after the barrier, so the
// compiler's vmcnt(0)-before-barrier waits on loads that landed during compute(t).
// Uniform grid: 512 blocks x exactly 34 k-steps. idx<8: qt'=8+idx steps [0,34) (partial);
// idx>=8: qtA=idx-8 full [0,4qtA+4) direct, then qt'=15-qtA steps [34, 64-4qtA) (partial).
__global__ __launch_bounds__(256, 3) void flash_attn(
    const bf16_t* __restrict__ Q, const bf16_t* __restrict__ Kg,
    const bf16_t* __restrict__ Vt, bf16_t* __restrict__ O,
    bf16_t* __restrict__ PO, float* __restrict__ ML) {
  __shared__ __align__(16) bf16_t lK[2][KT * 128];   // [j][d] chunks, swizzled; 2x8KB
  __shared__ __align__(16) bf16_t lV[2][128 * KT];   // [d][j] chunks, swizzled; 2x8KB
  __shared__ __align__(16) bf16_t lP[128 * 40];      // P^T as [q][j], stride 40; 10KB
  const int g = blockIdx.x;
  const int bh = g & 31, idx = g >> 5;
  const int t = threadIdx.x;
  const int w = t >> 6, lane = t & 63;
  const int la = lane & 15, lb = lane >> 4;
  const int qloc = w * 32 + la;

  const bf16_t* Qb = Q + (size_t)bh * SEQ * HDIM;
  const bf16_t* Kb = Kg + (size_t)bh * SEQ * HDIM;
  const bf16_t* Vb = Vt + (size_t)bh * HDIM * SEQ;
  const int b = bh >> 4, h = bh & 15;

  int nph, qts[2], k0s[2], k1s[2], slots[2];
  bool parts[2];
  if (idx < 8) {
    nph = 1; qts[0] = 8 + idx; k0s[0] = 0; k1s[0] = 34;
    parts[0] = true; slots[0] = (idx * 32 + bh) * 2;
  } else {
    int qtA = idx - 8;
    nph = 2;
    qts[0] = qtA; k0s[0] = 0; k1s[0] = 4 * qtA + 4; parts[0] = false; slots[0] = 0;
    qts[1] = 15 - qtA; k0s[1] = 34; k1s[1] = 64 - 4 * qtA;
    parts[1] = true; slots[1] = ((7 - qtA) * 32 + bh) * 2 + 1;
  }

  // staging lane roles (fixed per thread)
  const int kj = t >> 4, kcc = t & 15;           // K: 2 iters cover 32 rows x 16 chunks
  const int vd = t >> 2, vjc = t & 3;            // V: 2 iters cover 128 rows x 4 chunks

  for (int ph = 0; ph < nph; ph++) {
    const int qt = qts[ph], kt0 = k0s[ph], kt1 = k1s[ph];
    const int q0 = qt * 128;

    // Q fragments (B-operand): Q[q0+qloc+16mt][32ks+8lb+i], prescaled by QSCALE
    bf16x8_t qf[2][4];
#pragma unroll
    for (int mt = 0; mt < 2; mt++)
#pragma unroll
      for (int ks = 0; ks < 4; ks++)
        qf[mt][ks] = *(const bf16x8_t*)(Qb + (size_t)(q0 + qloc + mt * 16) * HDIM + ks * 32 + lb * 8);

    f32x4 oacc[2][8];
    float mr[2] = {MINIT, MINIT}, lr[2] = {0.f, 0.f};
    f32x4 zero = {0.f, 0.f, 0.f, 0.f};
#pragma unroll
    for (int mt = 0; mt < 2; mt++)
#pragma unroll
      for (int dt = 0; dt < 8; dt++) oacc[mt][dt] = zero;

    // prefetch first tile (barrier protects buffers still read by previous phase)
    __syncthreads();
    {
      const int j0 = kt0 * KT;
      int buf = kt0 & 1;
#pragma unroll
      for (int i = 0; i < 2; i++) {
        int j = kj + 16 * i;
        load_lds16(Kb + (size_t)(j0 + j) * HDIM + (((kcc ^ (j & 15))) * 8),
                   lK[buf] + (t + 256 * i) * 8);
      }
#pragma unroll
      for (int i = 0; i < 2; i++) {
        int d = vd + 64 * i;
        load_lds16(Vb + (size_t)d * SEQ + j0 + (((vjc ^ ((d & 3) ^ ((d >> 2) & 3)))) * 8),
                   lV[buf] + (t + 256 * i) * 8);
      }
    }

    for (int kt = kt0; kt < kt1; kt++) {
      const int j0 = kt * KT;
      const int cur = kt & 1;
      __syncthreads();  // waits stage(kt); cheap when prefetched a full compute-phase ago

      if (kt + 1 < kt1) {  // prefetch tile kt+1 into the other buffer
        const int jn = (kt + 1) * KT;
        const int nb = cur ^ 1;
#pragma unroll
        for (int i = 0; i < 2; i++) {
          int j = kj + 16 * i;
          load_lds16(Kb + (size_t)(jn + j) * HDIM + (((kcc ^ (j & 15))) * 8),
                     lK[nb] + (t + 256 * i) * 8);
        }
#pragma unroll
        for (int i = 0; i < 2; i++) {
          int d = vd + 64 * i;
          load_lds16(Vb + (size_t)d * SEQ + jn + (((vjc ^ ((d & 3) ^ ((d >> 2) & 3)))) * 8),
                     lV[nb] + (t + 256 * i) * 8);
        }
      }

      // S^T = K Q^T : rows j (2 nt tiles of 16), cols q (2 mt tiles)
      f32x4 st[2][2];
#pragma unroll
      for (int nt = 0; nt < 2; nt++)
#pragma unroll
        for (int mt = 0; mt < 2; mt++) st[nt][mt] = zero;
#pragma unroll
      for (int ks = 0; ks < 4; ks++) {
#pragma unroll
        for (int nt = 0; nt < 2; nt++) {
          int j = nt * 16 + la;
          int ck = (ks * 4 + lb) ^ (j & 15);
          bf16x8_t kf = *(const bf16x8_t*)(lK[cur] + j * 128 + ck * 8);
#pragma unroll
          for (int mt = 0; mt < 2; mt++)
            st[nt][mt] = __builtin_amdgcn_mfma_f32_16x16x32_bf16(kf, qf[mt][ks], st[nt][mt], 0, 0, 0);
        }
      }

      const bool dm = (j0 + KT > q0);  // diagonal-straddling (block-uniform)
#pragma unroll
      for (int mt = 0; mt < 2; mt++) {
        int qg = q0 + qloc + mt * 16;
        if (dm) {
#pragma unroll
          for (int nt = 0; nt < 2; nt++)
#pragma unroll
            for (int r = 0; r < 4; r++)
              if (j0 + nt * 16 + lb * 4 + r > qg) st[nt][mt][r] = NEGI;
        }
        float tm = NEGI;
#pragma unroll
        for (int nt = 0; nt < 2; nt++)
#pragma unroll
          for (int r = 0; r < 4; r++) tm = fmaxf(tm, st[nt][mt][r]);
        tm = fmaxf(tm, __shfl_xor(tm, 16));
        tm = fmaxf(tm, __shfl_xor(tm, 32));
        float mnew = fmaxf(mr[mt], tm);
        float alpha = exp2f(mr[mt] - mnew);
        mr[mt] = mnew;
        lr[mt] *= alpha;
#pragma unroll
        for (int dt = 0; dt < 8; dt++) oacc[mt][dt] *= alpha;
        float s = 0.f;
#pragma unroll
        for (int nt = 0; nt < 2; nt++) {
          f32x4 p;
#pragma unroll
          for (int r = 0; r < 4; r++) {
            p[r] = exp2f(st[nt][mt][r] - mnew);
            s += p[r];
          }
          bf16x4_t pk;
          pk.x = (bf16_t)p[0]; pk.y = (bf16_t)p[1]; pk.z = (bf16_t)p[2]; pk.w = (bf16_t)p[3];
          *(bf16x4_t*)(lP + (qloc + mt * 16) * 40 + nt * 16 + lb * 4) = pk;
        }
        s += __shfl_xor(s, 16);
        s += __shfl_xor(s, 32);
        lr[mt] += s;
      }

      // O^T += V^T P^T  (K-dim = 32 -> single ks)
      bf16x8_t pf[2];
#pragma unroll
      for (int mt = 0; mt < 2; mt++)
        pf[mt] = *(const bf16x8_t*)(lP + (w * 32 + mt * 16 + la) * 40 + lb * 8);
#pragma unroll
      for (int dt = 0; dt < 8; dt++) {
        int d = dt * 16 + la;
        int jc = lb ^ ((d & 3) ^ ((d >> 2) & 3));
        bf16x8_t vf = *(const bf16x8_t*)(lV[cur] + d * 32 + jc * 8);
#pragma unroll
        for (int mt = 0; mt < 2; mt++)
          oacc[mt][dt] = __builtin_amdgcn_mfma_f32_16x16x32_bf16(vf, pf[mt], oacc[mt][dt], 0, 0, 0);
      }
    }

    if (!parts[ph]) {
#pragma unroll
      for (int mt = 0; mt < 2; mt++) {
        float inv = 1.0f / lr[mt];
        int q = q0 + qloc + mt * 16;
        bf16_t* dst = O + ((size_t)b * SEQ + q) * D_MODEL + h * HDIM + lb * 4;
#pragma unroll
        for (int dt = 0; dt < 8; dt++) {
          f32x4 v = oacc[mt][dt];
          bf16x4_t pk;
          pk.x = (bf16_t)(v[0] * inv); pk.y = (bf16_t)(v[1] * inv);
          pk.z = (bf16_t)(v[2] * inv); pk.w = (bf16_t)(v[3] * inv);
          *(bf16x4_t*)(dst + dt * 16) = pk;
        }
      }
    } else {
      const int slot = slots[ph];
      bf16_t* pob = PO + (size_t)slot * 128 * 128;
#pragma unroll
      for (int mt = 0; mt < 2; mt++) {
        int q = qloc + mt * 16;
        bf16_t* dst = pob + (size_t)q * 128 + lb * 4;
#pragma unroll
        for (int dt = 0; dt < 8; dt++) {
          f32x4 v = oacc[mt][dt];
          bf16x4_t pk;
          pk.x = (bf16_t)v[0]; pk.y = (bf16_t)v[1];
          pk.z = (bf16_t)v[2]; pk.w = (bf16_t)v[3];
          *(bf16x4_t*)(dst + dt * 16) = pk;
        }
        if (lb == 0) {
          float2 ml = make_float2(mr[mt], lr[mt]);
          *(float2*)(ML + ((size_t)slot * 128 + q) * 2) = ml;
        }
      }
    }
  }
}

// ---------------------------------------------------------------- merge split-j partials
__global__ void merge_kernel(const bf16_t* __restrict__ PO, const float* __restrict__ ML,
                             bf16_t* __restrict__ O) {
  const int qti = blockIdx.x >> 5, bh = blockIdx.x & 31;
  const int qt = 8 + qti;
  const int t = threadIdx.x;
  const int q = t >> 1, dh = (t & 1) * 64;
  const size_t s1 = ((size_t)(qti * 32 + bh)) * 2;
  const float* ml1 = ML + (s1 * 128 + q) * 2;
  const float* ml2 = ML + ((s1 + 1) * 128 + q) * 2;
  float m1 = ml1[0], l1 = ml1[1], m2 = ml2[0], l2 = ml2[1];
  float m = fmaxf(m1, m2);
  float w1 = exp2f(m1 - m), w2 = exp2f(m2 - m);
  float inv = 1.0f / (w1 * l1 + w2 * l2);
  w1 *= inv; w2 *= inv;
  const bf16_t* p1 = PO + (s1 * 128 + q) * 128 + dh;
  const bf16_t* p2 = PO + ((s1 + 1) * 128 + q) * 128 + dh;
  const int b = bh >> 4, h = bh & 15;
  bf16_t* dst = O + ((size_t)b * SEQ + qt * 128 + q) * D_MODEL + h * HDIM + dh;
#pragma unroll
  for (int i = 0; i < 8; i++) {
    bf16x8_t a = ((const bf16x8_t*)p1)[i];
    bf16x8_t c = ((const bf16x8_t*)p2)[i];
    bf16x8_t o;
#pragma unroll
    for (int e = 0; e < 8; e++)
      o[e] = (bf16_t)(w1 * (float)a[e] + w2 * (float)c[e]);
    ((bf16x8_t*)dst)[i] = o;
  }
}

// ---------------------------------------------------------------- launch
extern "C" void kernel_launch(void* const* d_in, const int* in_sizes, int n_in,
                              void* d_out, int out_size, void* d_ws, size_t ws_size,
                              hipStream_t stream) {
  (void)in_sizes; (void)n_in; (void)out_size; (void)ws_size;
  const float* x  = (const float*)d_in[0];
  const float* Wq = (const float*)d_in[2];
  const float* bq = (const float*)d_in[3];
  const float* Wk = (const float*)d_in[4];
  const float* bk = (const float*)d_in[5];
  const float* Wv = (const float*)d_in[6];
  const float* bv = (const float*)d_in[7];
  const float* Wo = (const float*)d_in[8];
  const float* bo = (const float*)d_in[9];
  float* out = (float*)d_out;

  const size_t NBF = (size_t)MTOT * D_MODEL * sizeof(bf16_t);    // 16.8 MB
  const size_t WBF = (size_t)D_MODEL * D_MODEL * sizeof(bf16_t); // 8.4 MB
  char* p = (char*)d_ws;
  bf16_t* xb   = (bf16_t*)p; p += NBF;       // reused as attention output O
  bf16_t* Wcat = (bf16_t*)p; p += 4 * WBF;   // [Wq|Wk|Wv|Wo] bf16
  bf16_t* Qb   = (bf16_t*)p; p += NBF;
  bf16_t* Kb   = (bf16_t*)p; p += NBF;
  bf16_t* Vtb  = (bf16_t*)p; p += NBF;
  bf16_t* Wob  = Wcat + (size_t)3 * D_MODEL * D_MODEL;
  bf16_t* Ob   = xb;
  // Partial buffers overlay dead Wq|Wk|Wv bf16 slots (dead after QKV GEMM):
  bf16_t* PO = Wcat;                                     // 512 slots * 16384 bf16 = 16.8 MB
  float*  ML = (float*)(Wcat + (size_t)512 * 128 * 128); // 0.5 MB

  const int WN4 = D_MODEL * D_MODEL / 4;
  const int XN4 = MTOT * D_MODEL / 4;
  cast_kernel<<<XN4 / 256, 256, 0, stream>>>(x, xb, XN4);
  cast4_kernel<<<dim3(WN4 / 256, 4), 256, 0, stream>>>(Wq, Wk, Wv, Wo, Wcat, WN4);

  gemm_fused<<<dim3(MTOT / 128, 6144 / 128), 256, 0, stream>>>(
      xb, Wcat, 0, bq, bk, bv, Qb, Kb, Vtb, nullptr);

  flash_attn<<<dim3(512), 256, 0, stream>>>(Qb, Kb, Vtb, Ob, PO, ML);
  merge_kernel<<<dim3(256), 256, 0, stream>>>(PO, ML, Ob);

  gemm_fused<<<dim3(MTOT / 128, D_MODEL / 128), 256, 0, stream>>>(
      Ob, Wob, 1, bo, nullptr, nullptr, nullptr, nullptr, nullptr, out);
}